// Round 9
// baseline (277.414 us; speedup 1.0000x reference)
//
#include <hip/hip_runtime.h>
#include <stdint.h>

// Problem constants (match reference)
#define B_TOT 4096
#define T_LEN 2048
#define D_IN  10
#define OUT_N 30
#define CSTEP 32                        // timesteps per chunk
#define NCH   (T_LEN/CSTEP)             // 64 chunks
#define SMP_BLK 16                      // samples per block
#define XBUF_F (CSTEP*SMP_BLK*D_IN)     // 5120 floats = 20 KB per X buffer
#define ABUF_F (CSTEP*SMP_BLK*16)       // 8192 floats = 32 KB per xacc buffer
#define NLD   (XBUF_F/(4*64))           // width-4 loads per producer wave = 20
#define CH_BYTES (CSTEP*D_IN*4)         // global X advance per chunk = 1280 B

// async global->LDS, width 4 (per-lane arbitrary global addr, linear LDS dest)
#define GLD4(gptr, lptr) __builtin_amdgcn_global_load_lds( \
    (const __attribute__((address_space(1))) void*)(gptr),  \
    (__attribute__((address_space(3))) void*)(lptr), 4, 0, 0)

// DPP cross-lane move (VALU pipe). quad_perm broadcast k: ctrl=k*0x55.
// row_ror:N: ctrl=0x120+N -> dest lane i receives src lane (i-N) mod 16.
template<int CTRL>
__device__ __forceinline__ float dppf(float x) {
    return __int_as_float(
        __builtin_amdgcn_mov_dpp(__float_as_int(x), CTRL, 0xF, 0xF, true));
}

// raw v_exp_f32 (2^x) — used only in the head kernel's softmax
__device__ __forceinline__ float fast_exp2(float x) {
#if __has_builtin(__builtin_amdgcn_exp2f)
    return __builtin_amdgcn_exp2f(x);
#else
    float r; asm("v_exp_f32 %0, %1" : "=v"(r) : "v"(x)); return r;
#endif
}

// Trans-free rational tanh (Eigen/XLA minimax): ONE rcp on the dependency
// chain instead of exp2->add->rcp. Valid after clamp to +-7.90531; abs err
// ~1e-6 over the clamp range.
__device__ __forceinline__ float tanh_fast(float x) {
    const float B = 7.90531110763549805f;
    x = fminf(fmaxf(x, -B), B);
    float q = x * x;
    // num = x * (((((a13*q+a11)q+a9)q+a7)q+a5)q+a3)q+a1)
    float n = fmaf(q, -2.76076847742355e-16f, 2.00018790482477e-13f);
    n = fmaf(q, n, -8.60467152213735e-11f);
    n = fmaf(q, n,  5.12229709037114e-08f);
    n = fmaf(q, n,  1.48572235717979e-05f);
    n = fmaf(q, n,  6.37261928875436e-04f);
    n = fmaf(q, n,  4.89352455891786e-03f);
    n = n * x;
    // den = ((b6*q+b4)q+b2)q+b0
    float d = fmaf(q, 1.19825839466702e-06f, 1.18534705686654e-04f);
    d = fmaf(q, d, 2.26843463243900e-03f);
    d = fmaf(q, d, 4.89352518554385e-03f);
    return n * __builtin_amdgcn_rcpf(d);
}

// Producer/consumer LSTM scan.
// Block = 512 threads = 8 waves: waves 0-3 consumers (4 samples each, 16
// lanes/sample), waves 4-7 producers (compute xacc = s*(W_ih x + b) for the
// matching 4 samples, one chunk ahead, into double-buffered LDS).
// 256 blocks -> 1 block/CU, 2 waves/SIMD with DISJOINT work.
// R9 change: both activation stages use tanh_fast (rational, 1 rcp) instead
// of exp2+rcp: sigma(z) = 0.5 + 0.5*tanhE(z/2)  (weights pre-scaled by 0.5),
// tanh(z) = tanhE(z); cell state c kept in NATURAL domain; h = go * tanhE(c).
// Within a 16-lane group (one DPP row): u=(lr>>2)&3, tau=lr&3, weight row
// rw = tau*4+u (PyTorch i,f,g,o).
__launch_bounds__(512, 2)
__global__ void lstm_scan_kernel(const float* __restrict__ X,
                                 const float* __restrict__ W_ih,
                                 const float* __restrict__ W_hh,
                                 const float* __restrict__ b_ih,
                                 const float* __restrict__ b_hh,
                                 float* __restrict__ hT)
{
    __shared__ float xbuf[2][XBUF_F];   // 40 KB: X chunks [t][s][10]
    __shared__ float abuf[2][ABUF_F];   // 64 KB: xacc chunks [t][s][16]

    const int tid  = threadIdx.x;
    const int lane = tid & 63;
    const int w    = tid >> 6;          // wave in block (0..7)
    const int lr   = lane & 15;         // position within 16-lane group
    const int grp  = lane >> 4;         // sample within wave (0..3)
    const int u    = (lr >> 2) & 3;     // hidden unit
    const int tau  = lr & 3;            // 0=i,1=f,2=g,3=o
    const int rw   = tau * 4 + u;       // weight row
    const uint32_t samp0 = (uint32_t)blockIdx.x * SMP_BLK;

    // argument pre-scale: sigma lanes get 0.5 (sigma(z)=0.5+0.5*T(z/2)),
    // g-lane gets 1.0 (tanh directly)
    const float sarg = (tau == 2) ? 1.0f : 0.5f;

    if (w >= 4) {
        // ---------------- PRODUCER ----------------
        const int pw = w - 4;
        const int sg = pw * 4 + grp;    // sample within block (0..15)
        float wih[10];
        #pragma unroll
        for (int d0 = 0; d0 < 10; ++d0) wih[d0] = W_ih[rw*10 + d0] * sarg;
        const float bsum = (b_ih[rw] + b_hh[rw]) * sarg;

        // staging offsets: element p = [t][s][d] within a chunk
        uint32_t voff[NLD];
        #pragma unroll
        for (int kk = 0; kk < NLD; ++kk) {
            int p   = (pw*NLD + kk)*64 + lane;
            int t   = p / 160;          // D_IN*SMP_BLK = 160
            int rem = p - t*160;
            int s   = rem / 10;
            int d0  = rem - s*10;
            voff[kk] = (samp0 + (uint32_t)s) * (uint32_t)(T_LEN*D_IN*4)
                     + (uint32_t)(t*40 + d0*4);
        }
        const char* Xc = (const char*)X;

        // xproj of one chunk from xbuf[bb] -> abuf[bb]
        auto produce = [&](int bb) {
            #pragma unroll 4
            for (int t = 0; t < CSTEP; ++t) {
                const float2* xp =
                    (const float2*)&xbuf[bb][(t*SMP_BLK + sg)*10];
                float2 x0 = xp[0], x1 = xp[1], x2 = xp[2],
                       x3 = xp[3], x4 = xp[4];
                float acc = bsum;
                acc = fmaf(wih[0], x0.x, acc); acc = fmaf(wih[1], x0.y, acc);
                acc = fmaf(wih[2], x1.x, acc); acc = fmaf(wih[3], x1.y, acc);
                acc = fmaf(wih[4], x2.x, acc); acc = fmaf(wih[5], x2.y, acc);
                acc = fmaf(wih[6], x3.x, acc); acc = fmaf(wih[7], x3.y, acc);
                acc = fmaf(wih[8], x4.x, acc); acc = fmaf(wih[9], x4.y, acc);
                abuf[bb][(t*SMP_BLK + sg)*16 + lr] = acc;
            }
        };

        // prologue: stage X(0)
        #pragma unroll
        for (int kk = 0; kk < NLD; ++kk)
            GLD4(Xc + voff[kk], &xbuf[0][(pw*NLD+kk)*64]);
        __syncthreads();                               // (1) X0 ready
        // stage X(1) (flies during compute), compute xacc(0)
        #pragma unroll
        for (int kk = 0; kk < NLD; ++kk)
            GLD4(Xc + (voff[kk] + CH_BYTES), &xbuf[1][(pw*NLD+kk)*64]);
        produce(0);
        __syncthreads();                               // (2) A0 + X1 ready

        for (int k = 0; k < NCH; ++k) {
            if (k + 1 < NCH) {
                if (k + 2 < NCH) {
                    const uint32_t add = (uint32_t)(k+2) * CH_BYTES;
                    #pragma unroll
                    for (int kk = 0; kk < NLD; ++kk)
                        GLD4(Xc + (voff[kk] + add),
                             &xbuf[k&1][(pw*NLD+kk)*64]);
                }
                produce((k+1)&1);
            }
            __syncthreads();
        }
    } else {
        // ---------------- CONSUMER ----------------
        __builtin_amdgcn_s_setprio(1);  // favor the serial-chain wave
        const int sg = w * 4 + grp;     // sample within block (0..15)
        // post-activation map: a = fma(k1, T, k0)
        //   tau=0,1,3 (i,f,o): sigma = 0.5*T + 0.5
        //   tau=2     (g):     tanh  = T
        const float k1 = (tau == 2) ? 1.0f : 0.5f;
        const float k0 = (tau == 2) ? 0.0f : 0.5f;
        // rotated W_hh columns to match row_ror data placement, pre-scaled
        const float whhA = W_hh[rw*4 +  u        ] * sarg;
        const float whhB = W_hh[rw*4 + ((u+3)&3)] * sarg;
        const float whhC = W_hh[rw*4 + ((u+2)&3)] * sarg;
        const float whhD = W_hh[rw*4 + ((u+1)&3)] * sarg;

        __syncthreads();                               // (1)
        __syncthreads();                               // (2)

        float c = 0.f, hown = 0.f;
        for (int k = 0; k < NCH; ++k) {
            const float* ab = &abuf[k&1][sg*16 + lr];  // step stride 256 floats
            // preload the whole chunk into registers: one wait, then a
            // pure-register 32-step serial loop (no LDS on the chain).
            float xr[CSTEP];
            #pragma unroll
            for (int t = 0; t < CSTEP; ++t) xr[t] = ab[t*256];
            #pragma unroll
            for (int t = 0; t < CSTEP; ++t) {
                // ---- serial chain for step t ----
                float hB = dppf<0x124>(hown);   // h[(u-1)&3]
                float hC = dppf<0x128>(hown);   // h[(u-2)&3]
                float hD = dppf<0x12C>(hown);   // h[(u+1)&3]
                float u1 = fmaf(whhA, hown, xr[t]);
                float acc = fmaf(whhB, hB, u1) + fmaf(whhD, hD, whhC * hC);
                float a  = fmaf(k1, tanh_fast(acc), k0);
                float gi = dppf<0x00>(a);       // sigmoid(i)
                float gf = dppf<0x55>(a);       // sigmoid(f)
                float gg = dppf<0xAA>(a);       // tanh(g)
                float go = dppf<0xFF>(a);       // sigmoid(o)
                c = fmaf(gf, c, gi * gg);
                hown = go * tanh_fast(c);
            }
            __syncthreads();
        }
        if (tau == 0) hT[(samp0 + sg)*4 + u] = hown;
    }
}

// Head: logits = hT @ W_out^T + b_out, then softmax. One thread per sample.
__global__ void head_kernel(const float* __restrict__ hT,
                            const float* __restrict__ W_out,
                            const float* __restrict__ b_out,
                            float* __restrict__ out)
{
    int b = blockIdx.x * blockDim.x + threadIdx.x;
    if (b >= B_TOT) return;
    float4 h = ((const float4*)hT)[b];
    float lg[OUT_N];
    float m = -1e30f;
    #pragma unroll
    for (int o = 0; o < OUT_N; ++o) {
        float v = b_out[o];
        v = fmaf(W_out[o*4+0], h.x, v);
        v = fmaf(W_out[o*4+1], h.y, v);
        v = fmaf(W_out[o*4+2], h.z, v);
        v = fmaf(W_out[o*4+3], h.w, v);
        lg[o] = v;
        m = fmaxf(m, v);
    }
    float s = 0.f;
    #pragma unroll
    for (int o = 0; o < OUT_N; ++o) {
        float e = fast_exp2((lg[o] - m) * 1.4426950408889634f);
        lg[o] = e;
        s += e;
    }
    float rs = 1.0f / s;
    #pragma unroll
    for (int o = 0; o < OUT_N; ++o) out[(size_t)b*OUT_N + o] = lg[o] * rs;
}

extern "C" void kernel_launch(void* const* d_in, const int* in_sizes, int n_in,
                              void* d_out, int out_size, void* d_ws, size_t ws_size,
                              hipStream_t stream)
{
    const float* X     = (const float*)d_in[0];
    const float* W_ih  = (const float*)d_in[1];
    const float* W_hh  = (const float*)d_in[2];
    const float* b_ih  = (const float*)d_in[3];
    const float* b_hh  = (const float*)d_in[4];
    const float* W_out = (const float*)d_in[5];
    const float* b_out = (const float*)d_in[6];
    float* out = (float*)d_out;
    float* hTs = (float*)d_ws;   // 4096*4 floats = 64 KB scratch

    lstm_scan_kernel<<<B_TOT/SMP_BLK, 512, 0, stream>>>(X, W_ih, W_hh, b_ih, b_hh, hTs);
    head_kernel<<<B_TOT/256, 256, 0, stream>>>(hTs, W_out, b_out, out);
}